// Round 13
// baseline (346.558 us; speedup 1.0000x reference)
//
#include <hip/hip_runtime.h>

#define B_ 8
#define C_ 3
#define H_ 512
#define W_ 1024
#define H2_ 256
#define W2_ 512
#define GAMMA_ 50.0f
#define NSUB 4

typedef __attribute__((ext_vector_type(2))) float v2f;

// acc layout (doubles in d_ws): quantity q, sub-slot s -> acc[q*NSUB+s], 28 doubles
// q: 0 pm2, 1 ddx2, 2 ddy2, 3 pm, 4 ddx, 5 ddy, 6 ssim

template <int NV>
__device__ __forceinline__ void reduce_acc(float (&v)[NV], double* acc, const int (&qidx)[NV]) {
    __shared__ float sred[NV][4];
    const int lane = threadIdx.x & 63;
    const int wave = threadIdx.x >> 6;
#pragma unroll
    for (int o = 32; o > 0; o >>= 1)
#pragma unroll
        for (int q = 0; q < NV; q++) v[q] += __shfl_down(v[q], o, 64);
    if (lane == 0)
#pragma unroll
        for (int q = 0; q < NV; q++) sred[q][wave] = v[q];
    __syncthreads();
    if (threadIdx.x == 0) {
#pragma unroll
        for (int q = 0; q < NV; q++) {
            float s = sred[q][0] + sred[q][1] + sred[q][2] + sred[q][3];
            atomicAdd(&acc[qidx[q] * NSUB + (blockIdx.x & (NSUB - 1))], (double)s);
        }
    }
}

__global__ void init_acc(double* acc) {
    if (threadIdx.x < 7 * NSUB) acc[threadIdx.x] = 0.0;
}

// normalized 11-tap Gaussian, sigma=1.5 (f32, matches jnp within rounding)
#define G0 0.0010283804f
#define G1 0.0075987582f
#define G2 0.0360007882f
#define G3 0.1093606949f
#define G4 0.2130055428f
#define G5 0.2660117248f

#define TH 16
#define TW 64
#define HALO_H (TH + 10)          // 26
#define HALO_W (TW + 10)          // 74
#define HALO_N (HALO_H * HALO_W)  // 1924
#define VW 75                     // records per row of vF

#define NHALF (B_ * H2_ * (W2_ / 4))  // 262144
#define NSMOOTH (B_ * H_ * (W_ / 4))  // 1048576
#define NTOT (NHALF + NSMOOTH)        // 1310720 = 5120 * 256
#define NSSIMBLK 8192                 // 16 z * 32 by * 16 bx

// record-index swizzle: injects bits 3,4 into bits 1,0 -> phase-conflict-free H reads
__device__ __forceinline__ int swz(int ridx) {
    return ridx ^ (((ridx >> 3) & 1) << 1) ^ ((ridx >> 4) & 1);
}

__global__ __launch_bounds__(256) void fused_kernel(
    const float* __restrict__ disp_l, const float* __restrict__ disp_r,
    const float* __restrict__ dL2, const float* __restrict__ dR2,
    const float* __restrict__ img_l, const float* __restrict__ img_r,
    const float* __restrict__ iL2, const float* __restrict__ iR2, double* acc) {
    __shared__ float2 sAB[HALO_N];   // (a=warp, b=target) raw halo    15392 B
    __shared__ float4 vF[TH * VW];   // (vA, vB, vAA+vBB, vAB) swz'd   19200 B

    const int bid = blockIdx.x;

    // ================= ssim + full-res pm path, XCD-banded tile decode ============
    // block bid runs on XCD (bid & 7); each XCD class owns a 4-tile-row y-band.
    const int xcd = bid & 7;
    const int t8 = bid >> 3;                 // 0..1023
    const int z = t8 >> 6;                   // 0..15
    const int r6 = t8 & 63;
    const int by = (xcd << 2) | (r6 >> 4);
    const int bx = r6 & 15;

    const int b = z >> 1;
    const int pair = z & 1;
    const float* samp = (pair == 0) ? img_r : img_l;
    const float* targ = (pair == 0) ? img_l : img_r;
    const float* disp = (pair == 0) ? disp_l : disp_r;
    const float sign = (pair == 0) ? -1.f : 1.f;

    const int x0t = bx * TW;
    const int y0t = by * TH;

    const float gg[11] = {G0, G1, G2, G3, G4, G5, G4, G3, G2, G1, G0};
    v2f w01[14], w23[14];
#pragma unroll
    for (int k = 0; k < 14; ++k) {
        w01[k].x = (k <= 10) ? gg[k] : 0.f;
        w01[k].y = (k >= 1 && k <= 11) ? gg[k - 1] : 0.f;
        w23[k].x = (k >= 2 && k <= 12) ? gg[k - 2] : 0.f;
        w23[k].y = (k >= 3) ? gg[k - 3] : 0.f;
    }

    // ---- phase 0: warp coordinates, once per (pair) — shared by all 3 channels ----
    int riy[8], gxa[8], gxb[8];
    float wxs[8];
    {
        const int bHW = b * (H_ * W_);
#pragma unroll
        for (int it = 0; it < 8; ++it) {
            const int idq = threadIdx.x + 256 * it;
            riy[it] = -1;
            if (idq < HALO_N) {
                const int i = idq / HALO_W;
                const int j = idq - i * HALO_W;
                const int iy = y0t + i - 5;
                const int ix = x0t + j - 5;
                if (iy >= 0 && iy < H_ && ix >= 0 && ix < W_) {
                    const int rr = iy * W_ + ix;
                    riy[it] = rr;
                    const float d = disp[bHW + rr];
                    float xn = fminf(fmaxf((float)ix + sign * d, 0.f), (float)(W_ - 1));
                    float xf = floorf(xn);
                    wxs[it] = xn - xf;
                    const int xi = (int)xf;
                    gxa[it] = iy * W_ + xi;
                    gxb[it] = gxa[it] + (xi < W_ - 1 ? 1 : 0);
                }
            }
        }
    }

    float pa0[8], pa1[8], pbv[8];
    auto prefetch = [&](int c) {
        const int cb = (b * C_ + c) * (H_ * W_);
#pragma unroll
        for (int it = 0; it < 8; ++it) {
            const int idq = threadIdx.x + 256 * it;
            if (idq < HALO_N && riy[it] >= 0) {
                pbv[it] = targ[cb + riy[it]];
                pa0[it] = samp[cb + gxa[it]];
                pa1[it] = samp[cb + gxb[it]];
            }
        }
    };

    float ssim_loc = 0.f, pm_loc = 0.f;

    const int hr = threadIdx.x >> 4;          // H-pass output row (uniform per 16 lanes)
    const int hc0 = (threadIdx.x & 15) << 2;  // H-pass output col group

    prefetch(0);

#pragma unroll 1
    for (int c = 0; c < C_; ++c) {
        // ---- write staged halo ----
#pragma unroll
        for (int it = 0; it < 8; ++it) {
            const int idq = threadIdx.x + 256 * it;
            if (idq < HALO_N) {
                float av = 0.f, bv = 0.f;
                if (riy[it] >= 0) {
                    const float wx = wxs[it];
                    av = pa0[it] * (1.f - wx) + pa1[it] * wx;
                    bv = pbv[it];
                }
                sAB[idq] = make_float2(av, bv);
            }
        }
        __syncthreads();

        if (c + 1 < C_) prefetch(c + 1);  // hide next channel's HBM latency

        // ---- vertical pass: (col j, 4 output rows), 14-tap slide, packed, + pm ----
#pragma unroll
        for (int it = 0; it < 2; ++it) {
            const int t = threadIdx.x + 256 * it;
            if (t < 4 * HALO_W) {
                const int q = t / HALO_W;
                const int j = t - q * HALO_W;
                const int r0 = q * 4;
                const bool jc = (j >= 5 && j < 69);
                v2f amA = 0.f, bmA = 0.f, ssA = 0.f, abA = 0.f;
                v2f amB = 0.f, bmB = 0.f, ssB = 0.f, abB = 0.f;
#pragma unroll
                for (int k = 0; k < 14; ++k) {
                    const float2 p = sAB[(r0 + k) * HALO_W + j];
                    const float sq = fmaf(p.y, p.y, p.x * p.x);  // aa+bb
                    const float ab = p.x * p.y;
                    const v2f wA = w01[k], wB = w23[k];
                    amA += wA * p.x;
                    bmA += wA * p.y;
                    ssA += wA * sq;
                    abA += wA * ab;
                    amB += wB * p.x;
                    bmB += wB * p.y;
                    ssB += wB * sq;
                    abB += wB * ab;
                    if (k >= 5 && k <= 8) {
                        if (jc) pm_loc += fabsf(p.x - p.y);
                    }
                }
                const int rb = r0 * VW + j;
                vF[swz(rb)] = make_float4(amA.x, bmA.x, ssA.x, abA.x);
                vF[swz(rb + VW)] = make_float4(amA.y, bmA.y, ssA.y, abA.y);
                vF[swz(rb + 2 * VW)] = make_float4(amB.x, bmB.x, ssB.x, abB.x);
                vF[swz(rb + 3 * VW)] = make_float4(amB.y, bmB.y, ssB.y, abB.y);
            }
        }
        __syncthreads();

        // ---- horizontal pass: (row hr, 4 output cols), 14-tap slide, packed ----
        {
            const int rowb = hr * VW + hc0;
            v2f m1A = 0.f, m2A = 0.f, qsA = 0.f, q12A = 0.f;
            v2f m1B = 0.f, m2B = 0.f, qsB = 0.f, q12B = 0.f;
#pragma unroll
            for (int k = 0; k < 14; ++k) {
                const float4 f = vF[swz(rowb + k)];
                const v2f wA = w01[k], wB = w23[k];
                m1A += wA * f.x;
                m2A += wA * f.y;
                qsA += wA * f.z;
                q12A += wA * f.w;
                m1B += wB * f.x;
                m2B += wB * f.y;
                qsB += wB * f.z;
                q12B += wB * f.w;
            }
            const float C1 = 1e-4f, C2 = 9e-4f;
            {
                const v2f mu1sq = m1A * m1A, mu2sq = m2A * m2A, mu12 = m1A * m2A;
                const v2f s12 = q12A - mu12, ss = qsA - mu1sq - mu2sq;
                const v2f num = (2.f * mu12 + C1) * (2.f * s12 + C2);
                const v2f den = (mu1sq + mu2sq + C1) * (ss + C2);
                const v2f r = num / den;
                ssim_loc += r.x + r.y;
            }
            {
                const v2f mu1sq = m1B * m1B, mu2sq = m2B * m2B, mu12 = m1B * m2B;
                const v2f s12 = q12B - mu12, ss = qsB - mu1sq - mu2sq;
                const v2f num = (2.f * mu12 + C1) * (2.f * s12 + C2);
                const v2f den = (mu1sq + mu2sq + C1) * (ss + C2);
                const v2f r = num / den;
                ssim_loc += r.x + r.y;
            }
        }
    }

    // ================= small-losses epilogue: one item per thread ==================
    // NTOT = 5120 * 256, so blocks 0..5119 each handle exactly 256 items.
    float pm2 = 0.f, sx2 = 0.f, sy2 = 0.f, sxf = 0.f, syf = 0.f;
    {
        const int i = bid * 256 + threadIdx.x;
        if (i < NHALF) {
            const int W4 = W2_ >> 2;
            const int HW = H2_ * W2_;
            const int xq = i % W4;
            const int x4 = xq << 2;
            const int yz = i / W4;
            const int y = yz % H2_;
            const int b2 = yz / H2_;
            const int p0 = (b2 * H2_ + y) * W2_ + x4;
            const int ib = ((b2 * C_) * H2_ + y) * W2_ + x4;
            const bool lastx = (x4 + 4 == W2_);
            const bool lasty = (y == H2_ - 1);

            float dl[5], dr[5];
            *(float4*)dl = *(const float4*)(dL2 + p0);
            *(float4*)dr = *(const float4*)(dR2 + p0);
            dl[4] = lastx ? 0.f : dL2[p0 + 4];
            dr[4] = lastx ? 0.f : dR2[p0 + 4];

            int xl0[4], xl1[4], xr0[4], xr1[4];
            float wxl[4], wxr[4];
#pragma unroll
            for (int t = 0; t < 4; t++) {
                float xn = fminf(fmaxf((float)(x4 + t) - dl[t], 0.f), (float)(W2_ - 1));
                float xf = floorf(xn);
                wxl[t] = xn - xf;
                xl0[t] = (int)xf;
                xl1[t] = xl0[t] + (xl0[t] < W2_ - 1 ? 1 : 0);
                float xm = fminf(fmaxf((float)(x4 + t) + dr[t], 0.f), (float)(W2_ - 1));
                float xg = floorf(xm);
                wxr[t] = xm - xg;
                xr0[t] = (int)xg;
                xr1[t] = xr0[t] + (xr0[t] < W2_ - 1 ? 1 : 0);
            }

            float axL[4] = {0, 0, 0, 0}, axR[4] = {0, 0, 0, 0};
            float ayL[4] = {0, 0, 0, 0}, ayR[4] = {0, 0, 0, 0};
#pragma unroll
            for (int ch = 0; ch < C_; ch++) {
                const float* pL = iL2 + ib + ch * HW;
                const float* pR = iR2 + ib + ch * HW;
                float vL[5], vR[5];
                *(float4*)vL = *(const float4*)pL;
                *(float4*)vR = *(const float4*)pR;
                vL[4] = lastx ? 0.f : pL[4];
                vR[4] = lastx ? 0.f : pR[4];
#pragma unroll
                for (int t = 0; t < 4; t++) {
                    axL[t] += fabsf(vL[t] - vL[t + 1]);
                    axR[t] += fabsf(vR[t] - vR[t + 1]);
                }
                if (!lasty) {
                    float wLr[4], wRr[4];
                    *(float4*)wLr = *(const float4*)(pL + W2_);
                    *(float4*)wRr = *(const float4*)(pR + W2_);
#pragma unroll
                    for (int t = 0; t < 4; t++) {
                        ayL[t] += fabsf(vL[t] - wLr[t]);
                        ayR[t] += fabsf(vR[t] - wRr[t]);
                    }
                }
                const float* gLrow = iR2 + ib - x4 + ch * HW;
                const float* gRrow = iL2 + ib - x4 + ch * HW;
#pragma unroll
                for (int t = 0; t < 4; t++) {
                    float wv = gLrow[xl0[t]] * (1.f - wxl[t]) + gLrow[xl1[t]] * wxl[t];
                    pm2 += fabsf(wv - vL[t]);
                    float wv2 = gRrow[xr0[t]] * (1.f - wxr[t]) + gRrow[xr1[t]] * wxr[t];
                    pm2 += fabsf(wv2 - vR[t]);
                }
            }
            const int nx = lastx ? 3 : 4;
#pragma unroll
            for (int t = 0; t < 4; t++) {
                if (t < nx) {
                    sx2 += fabsf(dl[t] - dl[t + 1]) * __expf(-GAMMA_ * (axL[t] * (1.f / 3.f)));
                    sx2 += fabsf(dr[t] - dr[t + 1]) * __expf(-GAMMA_ * (axR[t] * (1.f / 3.f)));
                }
            }
            if (!lasty) {
                float el[4], er[4];
                *(float4*)el = *(const float4*)(dL2 + p0 + W2_);
                *(float4*)er = *(const float4*)(dR2 + p0 + W2_);
#pragma unroll
                for (int t = 0; t < 4; t++) {
                    sy2 += fabsf(dl[t] - el[t]) * __expf(-GAMMA_ * (ayL[t] * (1.f / 3.f)));
                    sy2 += fabsf(dr[t] - er[t]) * __expf(-GAMMA_ * (ayR[t] * (1.f / 3.f)));
                }
            }
        } else if (i < NTOT) {
            const int s = i - NHALF;
            const int W4 = W_ >> 2;
            const int HW = H_ * W_;
            const int xq = s % W4;
            const int x4 = xq << 2;
            const int yz = s / W4;
            const int y = yz % H_;
            const int b2 = yz / H_;
            const int p0 = (b2 * H_ + y) * W_ + x4;
            const int ib = ((b2 * C_) * H_ + y) * W_ + x4;
            const bool lastx = (x4 + 4 == W_);
            const bool lasty = (y == H_ - 1);

            float axL[4] = {0, 0, 0, 0}, axR[4] = {0, 0, 0, 0};
            float ayL[4] = {0, 0, 0, 0}, ayR[4] = {0, 0, 0, 0};
#pragma unroll
            for (int ch = 0; ch < C_; ch++) {
                const float* pL = img_l + ib + ch * HW;
                const float* pR = img_r + ib + ch * HW;
                float vL[5], vR[5];
                *(float4*)vL = *(const float4*)pL;
                *(float4*)vR = *(const float4*)pR;
                vL[4] = lastx ? 0.f : pL[4];
                vR[4] = lastx ? 0.f : pR[4];
#pragma unroll
                for (int t = 0; t < 4; t++) {
                    axL[t] += fabsf(vL[t] - vL[t + 1]);
                    axR[t] += fabsf(vR[t] - vR[t + 1]);
                }
                if (!lasty) {
                    float wLr[4], wRr[4];
                    *(float4*)wLr = *(const float4*)(pL + W_);
                    *(float4*)wRr = *(const float4*)(pR + W_);
#pragma unroll
                    for (int t = 0; t < 4; t++) {
                        ayL[t] += fabsf(vL[t] - wLr[t]);
                        ayR[t] += fabsf(vR[t] - wRr[t]);
                    }
                }
            }
            float dl[5], dr[5];
            *(float4*)dl = *(const float4*)(disp_l + p0);
            *(float4*)dr = *(const float4*)(disp_r + p0);
            dl[4] = lastx ? 0.f : disp_l[p0 + 4];
            dr[4] = lastx ? 0.f : disp_r[p0 + 4];
            const int nx = lastx ? 3 : 4;
#pragma unroll
            for (int t = 0; t < 4; t++) {
                if (t < nx) {
                    sxf += fabsf(dl[t] - dl[t + 1]) * __expf(-GAMMA_ * (axL[t] * (1.f / 3.f)));
                    sxf += fabsf(dr[t] - dr[t + 1]) * __expf(-GAMMA_ * (axR[t] * (1.f / 3.f)));
                }
            }
            if (!lasty) {
                float el[4], er[4];
                *(float4*)el = *(const float4*)(disp_l + p0 + W_);
                *(float4*)er = *(const float4*)(disp_r + p0 + W_);
#pragma unroll
                for (int t = 0; t < 4; t++) {
                    syf += fabsf(dl[t] - el[t]) * __expf(-GAMMA_ * (ayL[t] * (1.f / 3.f)));
                    syf += fabsf(dr[t] - er[t]) * __expf(-GAMMA_ * (ayR[t] * (1.f / 3.f)));
                }
            }
        }
    }

    float vals[7] = {ssim_loc, pm_loc, pm2, sx2, sy2, sxf, syf};
    const int qidx[7] = {6, 3, 0, 1, 2, 4, 5};
    reduce_acc<7>(vals, acc, qidx);
}

__global__ void finalize_kernel(const double* __restrict__ acc, float* __restrict__ out) {
    if (threadIdx.x == 0 && blockIdx.x == 0) {
        double q[7];
        for (int i = 0; i < 7; i++) {
            q[i] = 0.0;
            for (int s = 0; s < NSUB; s++) q[i] += acc[i * NSUB + s];
        }
        const double N2 = (double)B_ * C_ * H2_ * W2_;
        const double Nx2 = (double)B_ * H2_ * (W2_ - 1);
        const double Ny2 = (double)B_ * (H2_ - 1) * W2_;
        const double N1 = (double)B_ * C_ * H_ * W_;
        const double Nx1 = (double)B_ * H_ * (W_ - 1);
        const double Ny1 = (double)B_ * (H_ - 1) * W_;
        double pm_d2 = q[0] / N2;
        double smooth_d2 = q[1] / Nx2 + q[2] / Ny2;
        double pm = q[3] / N1;
        double smooth = q[4] / Nx1 + q[5] / Ny1;
        double ssim_loss = 1.0 - q[6] / (2.0 * N1);
        double full = pm_d2 + 0.1 * smooth_d2 + pm + ssim_loss + 0.1 * smooth;
        double mon = 5.0 * pm + ssim_loss;
        out[0] = (float)full;
        out[1] = (float)mon;
    }
}

extern "C" void kernel_launch(void* const* d_in, const int* in_sizes, int n_in,
                              void* d_out, int out_size, void* d_ws, size_t ws_size,
                              hipStream_t stream) {
    const float* disp_l = (const float*)d_in[0];
    const float* disp_r = (const float*)d_in[1];
    const float* disp_ld2 = (const float*)d_in[2];
    const float* disp_rd2 = (const float*)d_in[3];
    const float* img_l = (const float*)d_in[4];
    const float* img_r = (const float*)d_in[5];
    const float* img_ld2 = (const float*)d_in[6];
    const float* img_rd2 = (const float*)d_in[7];
    double* acc = (double*)d_ws;
    float* out = (float*)d_out;

    hipLaunchKernelGGL(init_acc, dim3(1), dim3(64), 0, stream, acc);

    hipLaunchKernelGGL(fused_kernel, dim3(NSSIMBLK), dim3(256), 0, stream,
                       disp_l, disp_r, disp_ld2, disp_rd2,
                       img_l, img_r, img_ld2, img_rd2, acc);

    hipLaunchKernelGGL(finalize_kernel, dim3(1), dim3(1), 0, stream, acc, out);
}

// Round 14
// 192.999 us; speedup vs baseline: 1.7956x; 1.7956x over previous
//
#include <hip/hip_runtime.h>

#define B_ 8
#define C_ 3
#define H_ 512
#define W_ 1024
#define H2_ 256
#define W2_ 512
#define GAMMA_ 50.0f
#define NSUB 4

typedef __attribute__((ext_vector_type(2))) float v2f;

// acc layout (doubles in d_ws): quantity q, sub-slot s -> acc[q*NSUB+s], 28 doubles
// q: 0 pm2, 1 ddx2, 2 ddy2, 3 pm, 4 ddx, 5 ddy, 6 ssim

template <int NV>
__device__ __forceinline__ void reduce_acc(float (&v)[NV], double* acc, const int (&qidx)[NV]) {
    __shared__ float sred[NV][4];
    const int lane = threadIdx.x & 63;
    const int wave = threadIdx.x >> 6;
#pragma unroll
    for (int o = 32; o > 0; o >>= 1)
#pragma unroll
        for (int q = 0; q < NV; q++) v[q] += __shfl_down(v[q], o, 64);
    if (lane == 0)
#pragma unroll
        for (int q = 0; q < NV; q++) sred[q][wave] = v[q];
    __syncthreads();
    if (threadIdx.x == 0) {
        const int sub = blockIdx.x & (NSUB - 1);
#pragma unroll
        for (int q = 0; q < NV; q++) {
            float s = sred[q][0] + sred[q][1] + sred[q][2] + sred[q][3];
            atomicAdd(&acc[qidx[q] * NSUB + sub], (double)s);
        }
    }
}

__global__ void init_acc(double* acc) {
    if (threadIdx.x < 7 * NSUB) acc[threadIdx.x] = 0.0;
}

// normalized 11-tap Gaussian, sigma=1.5 (f32, matches jnp within rounding)
#define G0 0.0010283804f
#define G1 0.0075987582f
#define G2 0.0360007882f
#define G3 0.1093606949f
#define G4 0.2130055428f
#define G5 0.2660117248f

#define TH 16
#define TW 64
#define HALO_H (TH + 10)          // 26
#define HALO_W (TW + 10)          // 74
#define HALO_N (HALO_H * HALO_W)  // 1924
#define VW 75                     // records per row of vF

#define NHALF (B_ * H2_ * (W2_ / 4))  // 262144
#define NSMOOTH (B_ * H_ * (W_ / 4))  // 1048576
#define NTOT (NHALF + NSMOOTH)
#define NSMALLBLK 1024
#define NSSIMBLK 8192  // 16 z * 32 by * 16 bx

// record-index swizzle: injects bits 3,4 into bits 1,0 -> phase-conflict-free H reads
__device__ __forceinline__ int swz(int ridx) {
    return ridx ^ (((ridx >> 3) & 1) << 1) ^ ((ridx >> 4) & 1);
}

__global__ __launch_bounds__(256) void fused_kernel(
    const float* __restrict__ disp_l, const float* __restrict__ disp_r,
    const float* __restrict__ dL2, const float* __restrict__ dR2,
    const float* __restrict__ img_l, const float* __restrict__ img_r,
    const float* __restrict__ iL2, const float* __restrict__ iR2, double* acc) {
    __shared__ float2 sAB[HALO_N];   // (a=warp, b=target) raw halo    15392 B
    __shared__ float4 vF[TH * VW];   // (vA, vB, vAA+vBB, vAB) swz'd   19200 B

    const int bid = blockIdx.x;
    const int grp = bid / 9;
    const int rem = bid - grp * 9;

    if (rem == 8) {
        // ================= small-losses path: half-res pm+smooth, full-res smooth ====
        float pm = 0.f, sx2 = 0.f, sy2 = 0.f, sxf = 0.f, syf = 0.f;
        for (int i = grp * blockDim.x + threadIdx.x; i < NTOT;
             i += NSMALLBLK * blockDim.x) {
            if (i < NHALF) {
                const int W4 = W2_ >> 2;
                const int HW = H2_ * W2_;
                const int xq = i % W4;
                const int x4 = xq << 2;
                const int yz = i / W4;
                const int y = yz % H2_;
                const int b = yz / H2_;
                const int p0 = (b * H2_ + y) * W2_ + x4;
                const int ib = ((b * C_) * H2_ + y) * W2_ + x4;
                const bool lastx = (x4 + 4 == W2_);
                const bool lasty = (y == H2_ - 1);

                float dl[5], dr[5];
                *(float4*)dl = *(const float4*)(dL2 + p0);
                *(float4*)dr = *(const float4*)(dR2 + p0);
                dl[4] = lastx ? 0.f : dL2[p0 + 4];
                dr[4] = lastx ? 0.f : dR2[p0 + 4];

                int xl0[4], xl1[4], xr0[4], xr1[4];
                float wxl[4], wxr[4];
#pragma unroll
                for (int t = 0; t < 4; t++) {
                    float xn = fminf(fmaxf((float)(x4 + t) - dl[t], 0.f), (float)(W2_ - 1));
                    float xf = floorf(xn);
                    wxl[t] = xn - xf;
                    xl0[t] = (int)xf;
                    xl1[t] = xl0[t] + (xl0[t] < W2_ - 1 ? 1 : 0);
                    float xm = fminf(fmaxf((float)(x4 + t) + dr[t], 0.f), (float)(W2_ - 1));
                    float xg = floorf(xm);
                    wxr[t] = xm - xg;
                    xr0[t] = (int)xg;
                    xr1[t] = xr0[t] + (xr0[t] < W2_ - 1 ? 1 : 0);
                }

                float axL[4] = {0, 0, 0, 0}, axR[4] = {0, 0, 0, 0};
                float ayL[4] = {0, 0, 0, 0}, ayR[4] = {0, 0, 0, 0};
#pragma unroll
                for (int ch = 0; ch < C_; ch++) {
                    const float* pL = iL2 + ib + ch * HW;
                    const float* pR = iR2 + ib + ch * HW;
                    float vL[5], vR[5];
                    *(float4*)vL = *(const float4*)pL;
                    *(float4*)vR = *(const float4*)pR;
                    vL[4] = lastx ? 0.f : pL[4];
                    vR[4] = lastx ? 0.f : pR[4];
#pragma unroll
                    for (int t = 0; t < 4; t++) {
                        axL[t] += fabsf(vL[t] - vL[t + 1]);
                        axR[t] += fabsf(vR[t] - vR[t + 1]);
                    }
                    if (!lasty) {
                        float wLr[4], wRr[4];
                        *(float4*)wLr = *(const float4*)(pL + W2_);
                        *(float4*)wRr = *(const float4*)(pR + W2_);
#pragma unroll
                        for (int t = 0; t < 4; t++) {
                            ayL[t] += fabsf(vL[t] - wLr[t]);
                            ayR[t] += fabsf(vR[t] - wRr[t]);
                        }
                    }
                    const float* gLrow = iR2 + ib - x4 + ch * HW;
                    const float* gRrow = iL2 + ib - x4 + ch * HW;
#pragma unroll
                    for (int t = 0; t < 4; t++) {
                        float wv = gLrow[xl0[t]] * (1.f - wxl[t]) + gLrow[xl1[t]] * wxl[t];
                        pm += fabsf(wv - vL[t]);
                        float wv2 = gRrow[xr0[t]] * (1.f - wxr[t]) + gRrow[xr1[t]] * wxr[t];
                        pm += fabsf(wv2 - vR[t]);
                    }
                }
                const int nx = lastx ? 3 : 4;
#pragma unroll
                for (int t = 0; t < 4; t++) {
                    if (t < nx) {
                        sx2 += fabsf(dl[t] - dl[t + 1]) * __expf(-GAMMA_ * (axL[t] * (1.f / 3.f)));
                        sx2 += fabsf(dr[t] - dr[t + 1]) * __expf(-GAMMA_ * (axR[t] * (1.f / 3.f)));
                    }
                }
                if (!lasty) {
                    float el[4], er[4];
                    *(float4*)el = *(const float4*)(dL2 + p0 + W2_);
                    *(float4*)er = *(const float4*)(dR2 + p0 + W2_);
#pragma unroll
                    for (int t = 0; t < 4; t++) {
                        sy2 += fabsf(dl[t] - el[t]) * __expf(-GAMMA_ * (ayL[t] * (1.f / 3.f)));
                        sy2 += fabsf(dr[t] - er[t]) * __expf(-GAMMA_ * (ayR[t] * (1.f / 3.f)));
                    }
                }
            } else {
                const int s = i - NHALF;
                const int W4 = W_ >> 2;
                const int HW = H_ * W_;
                const int xq = s % W4;
                const int x4 = xq << 2;
                const int yz = s / W4;
                const int y = yz % H_;
                const int b = yz / H_;
                const int p0 = (b * H_ + y) * W_ + x4;
                const int ib = ((b * C_) * H_ + y) * W_ + x4;
                const bool lastx = (x4 + 4 == W_);
                const bool lasty = (y == H_ - 1);

                float axL[4] = {0, 0, 0, 0}, axR[4] = {0, 0, 0, 0};
                float ayL[4] = {0, 0, 0, 0}, ayR[4] = {0, 0, 0, 0};
#pragma unroll
                for (int ch = 0; ch < C_; ch++) {
                    const float* pL = img_l + ib + ch * HW;
                    const float* pR = img_r + ib + ch * HW;
                    float vL[5], vR[5];
                    *(float4*)vL = *(const float4*)pL;
                    *(float4*)vR = *(const float4*)pR;
                    vL[4] = lastx ? 0.f : pL[4];
                    vR[4] = lastx ? 0.f : pR[4];
#pragma unroll
                    for (int t = 0; t < 4; t++) {
                        axL[t] += fabsf(vL[t] - vL[t + 1]);
                        axR[t] += fabsf(vR[t] - vR[t + 1]);
                    }
                    if (!lasty) {
                        float wLr[4], wRr[4];
                        *(float4*)wLr = *(const float4*)(pL + W_);
                        *(float4*)wRr = *(const float4*)(pR + W_);
#pragma unroll
                        for (int t = 0; t < 4; t++) {
                            ayL[t] += fabsf(vL[t] - wLr[t]);
                            ayR[t] += fabsf(vR[t] - wRr[t]);
                        }
                    }
                }
                float dl[5], dr[5];
                *(float4*)dl = *(const float4*)(disp_l + p0);
                *(float4*)dr = *(const float4*)(disp_r + p0);
                dl[4] = lastx ? 0.f : disp_l[p0 + 4];
                dr[4] = lastx ? 0.f : disp_r[p0 + 4];
                const int nx = lastx ? 3 : 4;
#pragma unroll
                for (int t = 0; t < 4; t++) {
                    if (t < nx) {
                        sxf += fabsf(dl[t] - dl[t + 1]) * __expf(-GAMMA_ * (axL[t] * (1.f / 3.f)));
                        sxf += fabsf(dr[t] - dr[t + 1]) * __expf(-GAMMA_ * (axR[t] * (1.f / 3.f)));
                    }
                }
                if (!lasty) {
                    float el[4], er[4];
                    *(float4*)el = *(const float4*)(disp_l + p0 + W_);
                    *(float4*)er = *(const float4*)(disp_r + p0 + W_);
#pragma unroll
                    for (int t = 0; t < 4; t++) {
                        syf += fabsf(dl[t] - el[t]) * __expf(-GAMMA_ * (ayL[t] * (1.f / 3.f)));
                        syf += fabsf(dr[t] - er[t]) * __expf(-GAMMA_ * (ayR[t] * (1.f / 3.f)));
                    }
                }
            }
        }
        float vals[5] = {pm, sx2, sy2, sxf, syf};
        const int qidx[5] = {0, 1, 2, 4, 5};
        reduce_acc<5>(vals, acc, qidx);
        return;
    }

    // ================= ssim + full-res pm path, XCD-banded tile decode ============
    // real XCD of this block ~= bid & 7 = (grp + rem) & 7 (9 ≡ 1 mod 8).
    // each XCD class owns a contiguous 4-tile-row y-band of every image.
    const int xcd = (grp + rem) & 7;
    const int t8 = grp >> 3;                 // 0..127
    const int idx = rem * 128 + t8;          // 0..1023  (bijective with (grp,rem))
    const int z = idx >> 6;                  // 0..15
    const int r6 = idx & 63;
    const int by = (xcd << 2) | (r6 >> 4);   // xcd*4 + 0..3
    const int bx = r6 & 15;

    const int b = z >> 1;
    const int pair = z & 1;
    const float* samp = (pair == 0) ? img_r : img_l;
    const float* targ = (pair == 0) ? img_l : img_r;
    const float* disp = (pair == 0) ? disp_l : disp_r;
    const float sign = (pair == 0) ? -1.f : 1.f;

    const int x0t = bx * TW;
    const int y0t = by * TH;

    const float gg[11] = {G0, G1, G2, G3, G4, G5, G4, G3, G2, G1, G0};
    v2f w01[14], w23[14];
#pragma unroll
    for (int k = 0; k < 14; ++k) {
        w01[k].x = (k <= 10) ? gg[k] : 0.f;
        w01[k].y = (k >= 1 && k <= 11) ? gg[k - 1] : 0.f;
        w23[k].x = (k >= 2 && k <= 12) ? gg[k - 2] : 0.f;
        w23[k].y = (k >= 3) ? gg[k - 3] : 0.f;
    }

    // ---- phase 0: warp coordinates, once per (pair) — shared by all 3 channels ----
    int riy[8], gxa[8], gxb[8];
    float wxs[8];
    {
        const int bHW = b * (H_ * W_);
#pragma unroll
        for (int it = 0; it < 8; ++it) {
            const int idq = threadIdx.x + 256 * it;
            riy[it] = -1;
            if (idq < HALO_N) {
                const int i = idq / HALO_W;
                const int j = idq - i * HALO_W;
                const int iy = y0t + i - 5;
                const int ix = x0t + j - 5;
                if (iy >= 0 && iy < H_ && ix >= 0 && ix < W_) {
                    const int rr = iy * W_ + ix;
                    riy[it] = rr;
                    const float d = disp[bHW + rr];
                    float xn = fminf(fmaxf((float)ix + sign * d, 0.f), (float)(W_ - 1));
                    float xf = floorf(xn);
                    wxs[it] = xn - xf;
                    const int xi = (int)xf;
                    gxa[it] = iy * W_ + xi;
                    gxb[it] = gxa[it] + (xi < W_ - 1 ? 1 : 0);
                }
            }
        }
    }

    float pa0[8], pa1[8], pbv[8];
    auto prefetch = [&](int c) {
        const int cb = (b * C_ + c) * (H_ * W_);
#pragma unroll
        for (int it = 0; it < 8; ++it) {
            const int idq = threadIdx.x + 256 * it;
            if (idq < HALO_N && riy[it] >= 0) {
                pbv[it] = targ[cb + riy[it]];
                pa0[it] = samp[cb + gxa[it]];
                pa1[it] = samp[cb + gxb[it]];
            }
        }
    };

    float ssim_loc = 0.f, pm_loc = 0.f;

    const int hr = threadIdx.x >> 4;          // H-pass output row (uniform per 16 lanes)
    const int hc0 = (threadIdx.x & 15) << 2;  // H-pass output col group

    prefetch(0);

#pragma unroll 1
    for (int c = 0; c < C_; ++c) {
        // ---- write staged halo ----
#pragma unroll
        for (int it = 0; it < 8; ++it) {
            const int idq = threadIdx.x + 256 * it;
            if (idq < HALO_N) {
                float av = 0.f, bv = 0.f;
                if (riy[it] >= 0) {
                    const float wx = wxs[it];
                    av = pa0[it] * (1.f - wx) + pa1[it] * wx;
                    bv = pbv[it];
                }
                sAB[idq] = make_float2(av, bv);
            }
        }
        __syncthreads();

        if (c + 1 < C_) prefetch(c + 1);  // hide next channel's HBM latency

        // ---- vertical pass: (col j, 4 output rows), 14-tap slide, packed, + pm ----
#pragma unroll
        for (int it = 0; it < 2; ++it) {
            const int t = threadIdx.x + 256 * it;
            if (t < 4 * HALO_W) {
                const int q = t / HALO_W;
                const int j = t - q * HALO_W;
                const int r0 = q * 4;
                const bool jc = (j >= 5 && j < 69);
                v2f amA = 0.f, bmA = 0.f, ssA = 0.f, abA = 0.f;
                v2f amB = 0.f, bmB = 0.f, ssB = 0.f, abB = 0.f;
#pragma unroll
                for (int k = 0; k < 14; ++k) {
                    const float2 p = sAB[(r0 + k) * HALO_W + j];
                    const float sq = fmaf(p.y, p.y, p.x * p.x);  // aa+bb
                    const float ab = p.x * p.y;
                    const v2f wA = w01[k], wB = w23[k];
                    amA += wA * p.x;
                    bmA += wA * p.y;
                    ssA += wA * sq;
                    abA += wA * ab;
                    amB += wB * p.x;
                    bmB += wB * p.y;
                    ssB += wB * sq;
                    abB += wB * ab;
                    if (k >= 5 && k <= 8) {
                        if (jc) pm_loc += fabsf(p.x - p.y);
                    }
                }
                const int rb = r0 * VW + j;
                vF[swz(rb)] = make_float4(amA.x, bmA.x, ssA.x, abA.x);
                vF[swz(rb + VW)] = make_float4(amA.y, bmA.y, ssA.y, abA.y);
                vF[swz(rb + 2 * VW)] = make_float4(amB.x, bmB.x, ssB.x, abB.x);
                vF[swz(rb + 3 * VW)] = make_float4(amB.y, bmB.y, ssB.y, abB.y);
            }
        }
        __syncthreads();

        // ---- horizontal pass: (row hr, 4 output cols), 14-tap slide, packed ----
        {
            const int rowb = hr * VW + hc0;
            v2f m1A = 0.f, m2A = 0.f, qsA = 0.f, q12A = 0.f;
            v2f m1B = 0.f, m2B = 0.f, qsB = 0.f, q12B = 0.f;
#pragma unroll
            for (int k = 0; k < 14; ++k) {
                const float4 f = vF[swz(rowb + k)];
                const v2f wA = w01[k], wB = w23[k];
                m1A += wA * f.x;
                m2A += wA * f.y;
                qsA += wA * f.z;
                q12A += wA * f.w;
                m1B += wB * f.x;
                m2B += wB * f.y;
                qsB += wB * f.z;
                q12B += wB * f.w;
            }
            const float C1 = 1e-4f, C2 = 9e-4f;
            {
                const v2f mu1sq = m1A * m1A, mu2sq = m2A * m2A, mu12 = m1A * m2A;
                const v2f s12 = q12A - mu12, ss = qsA - mu1sq - mu2sq;
                const v2f num = (2.f * mu12 + C1) * (2.f * s12 + C2);
                const v2f den = (mu1sq + mu2sq + C1) * (ss + C2);
                const v2f r = num / den;
                ssim_loc += r.x + r.y;
            }
            {
                const v2f mu1sq = m1B * m1B, mu2sq = m2B * m2B, mu12 = m1B * m2B;
                const v2f s12 = q12B - mu12, ss = qsB - mu1sq - mu2sq;
                const v2f num = (2.f * mu12 + C1) * (2.f * s12 + C2);
                const v2f den = (mu1sq + mu2sq + C1) * (ss + C2);
                const v2f r = num / den;
                ssim_loc += r.x + r.y;
            }
        }
    }

    float vals[2] = {ssim_loc, pm_loc};
    const int qidx[2] = {6, 3};
    reduce_acc<2>(vals, acc, qidx);
}

__global__ void finalize_kernel(const double* __restrict__ acc, float* __restrict__ out) {
    if (threadIdx.x == 0 && blockIdx.x == 0) {
        double q[7];
        for (int i = 0; i < 7; i++) {
            q[i] = 0.0;
            for (int s = 0; s < NSUB; s++) q[i] += acc[i * NSUB + s];
        }
        const double N2 = (double)B_ * C_ * H2_ * W2_;
        const double Nx2 = (double)B_ * H2_ * (W2_ - 1);
        const double Ny2 = (double)B_ * (H2_ - 1) * W2_;
        const double N1 = (double)B_ * C_ * H_ * W_;
        const double Nx1 = (double)B_ * H_ * (W_ - 1);
        const double Ny1 = (double)B_ * (H_ - 1) * W_;
        double pm_d2 = q[0] / N2;
        double smooth_d2 = q[1] / Nx2 + q[2] / Ny2;
        double pm = q[3] / N1;
        double smooth = q[4] / Nx1 + q[5] / Ny1;
        double ssim_loss = 1.0 - q[6] / (2.0 * N1);
        double full = pm_d2 + 0.1 * smooth_d2 + pm + ssim_loss + 0.1 * smooth;
        double mon = 5.0 * pm + ssim_loss;
        out[0] = (float)full;
        out[1] = (float)mon;
    }
}

extern "C" void kernel_launch(void* const* d_in, const int* in_sizes, int n_in,
                              void* d_out, int out_size, void* d_ws, size_t ws_size,
                              hipStream_t stream) {
    const float* disp_l = (const float*)d_in[0];
    const float* disp_r = (const float*)d_in[1];
    const float* disp_ld2 = (const float*)d_in[2];
    const float* disp_rd2 = (const float*)d_in[3];
    const float* img_l = (const float*)d_in[4];
    const float* img_r = (const float*)d_in[5];
    const float* img_ld2 = (const float*)d_in[6];
    const float* img_rd2 = (const float*)d_in[7];
    double* acc = (double*)d_ws;
    float* out = (float*)d_out;

    hipLaunchKernelGGL(init_acc, dim3(1), dim3(64), 0, stream, acc);

    hipLaunchKernelGGL(fused_kernel, dim3(NSSIMBLK + NSMALLBLK), dim3(256), 0, stream,
                       disp_l, disp_r, disp_ld2, disp_rd2,
                       img_l, img_r, img_ld2, img_rd2, acc);

    hipLaunchKernelGGL(finalize_kernel, dim3(1), dim3(1), 0, stream, acc, out);
}